// Round 7
// baseline (645.434 us; speedup 1.0000x reference)
//
#include <hip/hip_runtime.h>
#include <hip/hip_bf16.h>

#define NBATCH 8
#define CDIM 256
#define HH 64
#define WW 64
#define HWSZ 4096
#define TT 32768        // NBATCH * HWSZ tokens
#define QKVD 768        // q(256) | k(256) | v(256)
#define TOPK 4
#define HID 1024
#define ATTN_SCALE 0.0625f   // 256^-0.5

typedef __hip_bfloat16 bf16;
typedef __attribute__((ext_vector_type(8))) short s8v;   // 8 bf16 = 4 VGPR
typedef __attribute__((ext_vector_type(4))) float f4v;   // MFMA acc

__device__ __forceinline__ float toF(bf16 v) { return __bfloat162float(v); }
__device__ __forceinline__ bf16  toB(float v) { return __float2bfloat16(v); }

// ---------------------------------------------------------------------------
// Prep: fold gamma into weights, cast to bf16; build concat bias for qkv.
__global__ void k_prep(const float* __restrict__ wq, const float* __restrict__ gq,
                       const float* __restrict__ wkv, const float* __restrict__ gkv,
                       const float* __restrict__ wfc1, const float* __restrict__ gfc1,
                       const float* __restrict__ wfc2, const float* __restrict__ gfc2,
                       const float* __restrict__ bq, const float* __restrict__ bkv,
                       bf16* __restrict__ wbqkv, bf16* __restrict__ wbfc1,
                       bf16* __restrict__ wbfc2, float* __restrict__ bias768) {
    int i = blockIdx.x * 256 + threadIdx.x;
    if (i < 196608) {                       // wbqkv [768][256]
        int r = i >> 8;
        float g = (r < 256) ? gq[r] : gkv[r - 256];
        float w = (r < 256) ? wq[i] : wkv[i - 65536];
        wbqkv[i] = toB(w * g);
        if (i < 768) bias768[i] = (i < 256) ? bq[i] : bkv[i - 256];
    } else if (i < 458752) {                // wbfc1 [1024][256]
        int j = i - 196608;
        wbfc1[j] = toB(wfc1[j] * gfc1[j >> 8]);
    } else if (i < 720896) {                // wbfc2 [256][1024]
        int j = i - 458752;
        wbfc2[j] = toB(wfc2[j] * gfc2[j >> 10]);
    }
}

// ---------------------------------------------------------------------------
// x NCHW fp32 -> token-major bf16 xt[m][c]
__global__ void k_xt(const float* __restrict__ x, bf16* __restrict__ xt) {
    __shared__ float tile[32][33];
    int s0 = blockIdx.x * 32, c0 = blockIdx.y * 32, n = blockIdx.z;
    int tx = threadIdx.x, ty = threadIdx.y;
#pragma unroll
    for (int r = 0; r < 4; r++)
        tile[ty + r * 8][tx] = x[(size_t)n * CDIM * HWSZ + (size_t)(c0 + ty + r * 8) * HWSZ + s0 + tx];
    __syncthreads();
#pragma unroll
    for (int r = 0; r < 4; r++)
        xt[((size_t)n * HWSZ + s0 + ty + r * 8) * CDIM + c0 + tx] = toB(tile[tx][ty + r * 8]);
}

// ---------------------------------------------------------------------------
// Window means of x (fp32-exact routing path). Block=(n,c), thread=window p.
__global__ void k_xwin(const float* __restrict__ x, float* __restrict__ xwin) {
    int b = blockIdx.x;
    int n = b >> 8, c = b & 255;
    int p = threadIdx.x, wy = p >> 4, wx = p & 15;
    const float* pl = x + ((size_t)n * CDIM + c) * HWSZ;
    float s = 0.f;
#pragma unroll
    for (int dy = 0; dy < 4; dy++)
#pragma unroll
        for (int dx = 0; dx < 4; dx++)
            s += pl[(wy * 4 + dy) * WW + wx * 4 + dx];
    xwin[((size_t)(n << 8) + p) * 256 + c] = s * 0.0625f;
}

// ---------------------------------------------------------------------------
// qkwin[m][0:512] = (xwin @ [wq|wk]^T)*g + b  (fp32 vector GEMM, M=2048 K=256)
__global__ void k_qkwin(const float* __restrict__ xwin,
                        const float* __restrict__ wq, const float* __restrict__ wkv,
                        const float* __restrict__ gq, const float* __restrict__ bq,
                        const float* __restrict__ gkv, const float* __restrict__ bkv,
                        float* __restrict__ qkwin) {
    __shared__ float As[16][68];
    __shared__ float Bs[16][68];
    int m0 = blockIdx.x * 64, n0 = blockIdx.y * 64;
    int tid = threadIdx.x;
    int tx = tid & 15, ty = tid >> 4;
    float acc[4][4] = {};
    for (int k0 = 0; k0 < 256; k0 += 16) {
#pragma unroll
        for (int r = 0; r < 4; r++) {
            int lin = tid + r * 256;
            int row = lin >> 4, kk = lin & 15;
            As[kk][row] = xwin[(size_t)(m0 + row) * 256 + k0 + kk];
            int n = n0 + row;
            const float* wr = (n < 256) ? (wq + (size_t)n * 256) : (wkv + (size_t)(n - 256) * 256);
            Bs[kk][row] = wr[k0 + kk];
        }
        __syncthreads();
#pragma unroll
        for (int kk = 0; kk < 16; kk++) {
            float a[4], bb[4];
#pragma unroll
            for (int i = 0; i < 4; i++) a[i] = As[kk][tx * 4 + i];
#pragma unroll
            for (int j = 0; j < 4; j++) bb[j] = Bs[kk][ty * 4 + j];
#pragma unroll
            for (int i = 0; i < 4; i++)
#pragma unroll
                for (int j = 0; j < 4; j++) acc[i][j] += a[i] * bb[j];
        }
        __syncthreads();
    }
#pragma unroll
    for (int j = 0; j < 4; j++) {
        int n = n0 + ty * 4 + j;
        float gg = (n < 256) ? gq[n] : gkv[n - 256];
        float bb = (n < 256) ? bq[n] : bkv[n - 256];
#pragma unroll
        for (int i = 0; i < 4; i++)
            qkwin[(size_t)(m0 + tx * 4 + i) * 512 + n] = acc[i][j] * gg + bb;
    }
}

// ---------------------------------------------------------------------------
// Routing: top-4 over 256 windows (ties -> lower index, as jax top_k).
__global__ void k_route(const float* __restrict__ qkwin, int* __restrict__ topk) {
    __shared__ float qrow[256];
    __shared__ float vals[256];
    __shared__ float rv[256];
    __shared__ int ri[256];
    int b = blockIdx.x;
    int n = b >> 8, pq = b & 255;
    int tid = threadIdx.x;
    qrow[tid] = qkwin[((size_t)(n << 8) + pq) * 512 + tid];
    __syncthreads();
    const float* krow = qkwin + ((size_t)(n << 8) + tid) * 512 + 256;
    float dot = 0.f;
    for (int o = 0; o < 256; o++) dot += qrow[o] * krow[o];
    vals[tid] = dot;
    __syncthreads();
    for (int sel = 0; sel < TOPK; sel++) {
        rv[tid] = vals[tid];
        ri[tid] = tid;
        __syncthreads();
        for (int off = 128; off > 0; off >>= 1) {
            if (tid < off) {
                if (rv[tid + off] > rv[tid] ||
                    (rv[tid + off] == rv[tid] && ri[tid + off] < ri[tid])) {
                    rv[tid] = rv[tid + off];
                    ri[tid] = ri[tid + off];
                }
            }
            __syncthreads();
        }
        if (tid == 0) {
            topk[((size_t)(n << 8) + pq) * TOPK + sel] = ri[0];
            vals[ri[0]] = -INFINITY;
        }
        __syncthreads();
    }
}

// ---------------------------------------------------------------------------
// MFMA GEMM: C[m][n] = A[m][k] * Wb[n][k] + bias[n].  A token-major bf16,
// Wb bf16 (gamma folded), bias fp32, out token-major bf16.
// OUTMODE 1 (qkv): cols >= 512 additionally stored planar to out2 (V for LEPE).
template <int BM, int BN, int OUTMODE>
__global__ __launch_bounds__(256) void k_mfma(const bf16* __restrict__ A,
                                              const bf16* __restrict__ Wb,
                                              const float* __restrict__ bias,
                                              bf16* __restrict__ out,
                                              bf16* __restrict__ out2,
                                              int M, int N, int K) {
    constexpr int WROWS = BM / 2, WCOLS = BN / 2;     // per-wave quadrant
    constexpr int WM = WROWS / 16, WN = WCOLS / 16;   // 16x16 tiles per wave
    constexpr int CA = (BM * 4) / 256;                // s8v chunks/thread for A
    constexpr int CB = (BN * 4) / 256;
    __shared__ bf16 As[BM * 32];
    __shared__ bf16 Bs[BN * 32];
    int m0 = blockIdx.x * BM, n0 = blockIdx.y * BN;
    int tid = threadIdx.x;
    int w = tid >> 6, lane = tid & 63;
    int wr = w >> 1, wc = w & 1;
    int lm = lane & 15, lq = lane >> 4;
    f4v acc[WM][WN];
#pragma unroll
    for (int i = 0; i < WM; i++)
#pragma unroll
        for (int j = 0; j < WN; j++) acc[i][j] = (f4v){0.f, 0.f, 0.f, 0.f};

    for (int k0 = 0; k0 < K; k0 += 32) {
        s8v va[CA], vb[CB];
#pragma unroll
        for (int q = 0; q < CA; q++) {
            int c = tid + q * 256, row = c >> 2, col = c & 3;
            va[q] = *(const s8v*)(A + (size_t)(m0 + row) * K + k0 + col * 8);
        }
#pragma unroll
        for (int q = 0; q < CB; q++) {
            int c = tid + q * 256, row = c >> 2, col = c & 3;
            vb[q] = *(const s8v*)(Wb + (size_t)(n0 + row) * K + k0 + col * 8);
        }
        __syncthreads();   // previous iter's LDS reads done
#pragma unroll
        for (int q = 0; q < CA; q++) {
            int c = tid + q * 256, row = c >> 2, col = c & 3;
            *(s8v*)&As[row * 32 + col * 8] = va[q];
        }
#pragma unroll
        for (int q = 0; q < CB; q++) {
            int c = tid + q * 256, row = c >> 2, col = c & 3;
            *(s8v*)&Bs[row * 32 + col * 8] = vb[q];
        }
        __syncthreads();
        s8v af[WM], bfr[WN];
#pragma unroll
        for (int i = 0; i < WM; i++)
            af[i] = *(const s8v*)&As[(wr * WROWS + i * 16 + lm) * 32 + lq * 8];
#pragma unroll
        for (int j = 0; j < WN; j++)
            bfr[j] = *(const s8v*)&Bs[(wc * WCOLS + j * 16 + lm) * 32 + lq * 8];
#pragma unroll
        for (int i = 0; i < WM; i++)
#pragma unroll
            for (int j = 0; j < WN; j++)
                acc[i][j] = __builtin_amdgcn_mfma_f32_16x16x32_bf16(af[i], bfr[j], acc[i][j], 0, 0, 0);
    }
    // Epilogue. C/D layout: col(n) = lane&15, row(m) = (lane>>4)*4 + reg.
#pragma unroll
    for (int j = 0; j < WN; j++) {
        int n = n0 + wc * WCOLS + j * 16 + lm;
        float bb = bias[n];
#pragma unroll
        for (int i = 0; i < WM; i++) {
            int mb = m0 + wr * WROWS + i * 16 + lq * 4;
#pragma unroll
            for (int r = 0; r < 4; r++)
                out[(size_t)(mb + r) * N + n] = toB(acc[i][j][r] + bb);
            if (OUTMODE == 1 && n >= 512) {   // planar V copy (lane-uniform branch)
                bf16* dst = out2 + ((size_t)(mb >> 12) * CDIM + (n - 512)) * HWSZ + (mb & 4095);
#pragma unroll
                for (int r = 0; r < 4; r++) dst[r] = toB(acc[i][j][r] + bb);
            }
        }
    }
}

// ---------------------------------------------------------------------------
// LEPE planar, IN-PLACE on vpl: block owns plane (n,c); 64x64 plane in LDS.
__global__ void k_lepe_pl(bf16* __restrict__ vpl, const float* __restrict__ w_lepe,
                          const float* __restrict__ b_lepe) {
    __shared__ float pl[HWSZ];
    int b = blockIdx.x;
    int n = b >> 8, c = b & 255;
    int tid = threadIdx.x;
    bf16* plane = vpl + ((size_t)n * CDIM + c) * HWSZ;
#pragma unroll
    for (int k = 0; k < 16; k++) pl[tid + k * 256] = toF(plane[tid + k * 256]);
    float wreg[25];
#pragma unroll
    for (int i = 0; i < 25; i++) wreg[i] = w_lepe[c * 25 + i];
    float bias = b_lepe[c];
    __syncthreads();
#pragma unroll
    for (int k = 0; k < 16; k++) {
        int s = tid + k * 256;
        int y = s >> 6, xx0 = s & 63;
        float acc = bias;
#pragma unroll
        for (int dy = -2; dy <= 2; dy++) {
            int yy = y + dy;
            if (yy < 0 || yy >= HH) continue;
#pragma unroll
            for (int dx = -2; dx <= 2; dx++) {
                int xx = xx0 + dx;
                if (xx < 0 || xx >= WW) continue;
                acc += pl[yy * 64 + xx] * wreg[(dy + 2) * 5 + (dx + 2)];
            }
        }
        plane[s] = toB(acc);
    }
}

// ---------------------------------------------------------------------------
// MFMA attention: one block per (n, window). 256 thr = 4 waves, 2 heads/wave.
// S^T = K*Q^T (4 mfma) -> full softmax (all 64 keys present) -> P via LDS ->
// O = P*V^T (4 mfma) with V staged TRANSPOSED in LDS.
__global__ __launch_bounds__(256) void k_attn(const bf16* __restrict__ qkv,
                                              const int* __restrict__ topk,
                                              bf16* __restrict__ attnout) {
    __shared__ bf16 vst[256][72];      // V^T [dim][key], pad 72 (rows 144 B, 16-aligned)
    __shared__ bf16 plds[4][16][72];   // per-wave P [tok][key]
    __shared__ float lsm[4][16];       // per-wave softmax denominator per tok
    __shared__ int toks[64];           // routed key -> token index (within image)
    int b = blockIdx.x;
    int n = b >> 8, p = b & 255;
    int wy = p >> 4, wx = p & 15;
    int tid = threadIdx.x;
    if (tid < 64) {
        int rp = topk[((size_t)(n << 8) + p) * TOPK + (tid >> 4)] & 255;
        int st = tid & 15;
        toks[tid] = ((rp >> 4) * 4 + (st >> 2)) * WW + (rp & 15) * 4 + (st & 3);
    }
    __syncthreads();
    const bf16* qbase = qkv + (size_t)n * HWSZ * QKVD;
    // stage V^T: per pass, 64 keys x 32 dims. kt fast -> conflict-free-ish writes.
    {
        int kt = tid & 63, jj = tid >> 6;
#pragma unroll
        for (int pass = 0; pass < 8; pass++) {
            int d0 = pass * 32 + jj * 8;
            uint4 v = *(const uint4*)(qbase + (size_t)toks[kt] * QKVD + 512 + d0);
            const bf16* pv = (const bf16*)&v;
#pragma unroll
            for (int e = 0; e < 8; e++) vst[d0 + e][kt] = pv[e];
        }
    }
    __syncthreads();
    int w = tid >> 6, lane = tid & 63;
    int ln = lane & 15, lq = lane >> 4;
    int myS = (wy * 4 + (ln >> 2)) * WW + wx * 4 + (ln & 3);   // own-window token ln
    const f4v fz = {0.f, 0.f, 0.f, 0.f};
    for (int hh = 0; hh < 2; hh++) {
        int h = w * 2 + hh;
        // B-frag: Q[tok=ln][k=lq*8+j] straight from global
        s8v qf = *(const s8v*)(qbase + (size_t)myS * QKVD + h * 32 + lq * 8);
        // A-frags: K[key][k] per 16-key tile; S^T tiles
        f4v st4[4];
#pragma unroll
        for (int t = 0; t < 4; t++) {
            s8v kf = *(const s8v*)(qbase + (size_t)toks[t * 16 + ln] * QKVD + 256 + h * 32 + lq * 8);
            st4[t] = __builtin_amdgcn_mfma_f32_16x16x32_bf16(kf, qf, fz, 0, 0, 0);
        }
        // lane holds S[key = t*16+lq*4+r][tok = ln]; softmax over keys
        float mx = -INFINITY;
#pragma unroll
        for (int t = 0; t < 4; t++)
#pragma unroll
            for (int r = 0; r < 4; r++) mx = fmaxf(mx, st4[t][r]);
        mx = fmaxf(mx, __shfl_xor(mx, 16));
        mx = fmaxf(mx, __shfl_xor(mx, 32));
        mx *= ATTN_SCALE;
        float sum = 0.f;
#pragma unroll
        for (int t = 0; t < 4; t++)
#pragma unroll
            for (int r = 0; r < 4; r++) {
                float pp = __expf(st4[t][r] * ATTN_SCALE - mx);
                sum += pp;
                plds[w][ln][t * 16 + lq * 4 + r] = toB(pp);
            }
        sum += __shfl_xor(sum, 16);
        sum += __shfl_xor(sum, 32);
        if (lq == 0) lsm[w][ln] = sum;
        __syncthreads();
        // PV: A = P[tok][key] frags, B = V^T[dim][key] frags
        s8v ap0 = *(const s8v*)&plds[w][ln][lq * 8];
        s8v ap1 = *(const s8v*)&plds[w][ln][32 + lq * 8];
#pragma unroll
        for (int dt = 0; dt < 2; dt++) {
            int dim = h * 32 + dt * 16 + ln;
            s8v vv0 = *(const s8v*)&vst[dim][lq * 8];
            s8v vv1 = *(const s8v*)&vst[dim][32 + lq * 8];
            f4v o = __builtin_amdgcn_mfma_f32_16x16x32_bf16(ap0, vv0, fz, 0, 0, 0);
            o = __builtin_amdgcn_mfma_f32_16x16x32_bf16(ap1, vv1, o, 0, 0, 0);
            // C: col = dim_local(ln), row = tok = lq*4+r
#pragma unroll
            for (int r = 0; r < 4; r++) {
                int t = lq * 4 + r;
                float linv = 1.f / lsm[w][t];
                int s = (wy * 4 + (t >> 2)) * WW + wx * 4 + (t & 3);
                attnout[((size_t)n * HWSZ + s) * CDIM + dim] = toB(o[r] * linv);
            }
        }
        __syncthreads();   // before next head reuses plds/lsm
    }
}

// ---------------------------------------------------------------------------
// x1[s][c] = xt[s][c] + attn[s][c] + lepe_planar[c][s]  (in-place over xt)
__global__ void k_x1(const bf16* __restrict__ xt, const bf16* __restrict__ lepe,
                     const bf16* __restrict__ attnout, bf16* __restrict__ x1) {
    __shared__ float tile[32][33];
    int s0 = blockIdx.x * 32, c0 = blockIdx.y * 32, n = blockIdx.z;
    int tx = threadIdx.x, ty = threadIdx.y;
#pragma unroll
    for (int r = 0; r < 4; r++) {
        int c = c0 + ty + r * 8;
        tile[ty + r * 8][tx] = toF(lepe[((size_t)n * CDIM + c) * HWSZ + s0 + tx]);
    }
    __syncthreads();
#pragma unroll
    for (int r = 0; r < 4; r++) {
        int s = s0 + ty + r * 8;
        size_t idx = ((size_t)n * HWSZ + s) * CDIM + c0 + tx;
        x1[idx] = toB(toF(xt[idx]) + toF(attnout[idx]) + tile[tx][ty + r * 8]);
    }
}

// ---------------------------------------------------------------------------
// Depthwise 3x3 + bias + ReLU, token-major in/out, CHANNELS LANE-FAST.
// Block = 2 tokens x 128 cgroups; every tap load and the store are contiguous
// 1024-B-per-wave segments. Weights staged in LDS transposed to [tap][c][cg]
// so per-lane weight reads are stride-1 (conflict-free).
__global__ __launch_bounds__(256) void k_dw3_t(const bf16* __restrict__ h1,
                                               const float* __restrict__ w_dw,
                                               const float* __restrict__ b_dw,
                                               bf16* __restrict__ h1p) {
    __shared__ float wsm[9][8][128];   // 36 KB
    __shared__ float bsm[8][128];      // 4 KB
    int tid = threadIdx.x;
    for (int i = tid; i < 9216; i += 256) {
        int ch = i / 9, k = i - ch * 9;           // w_dw[ch*9+k]
        wsm[k][ch & 7][ch >> 3] = w_dw[i];
    }
    for (int i = tid; i < 1024; i += 256)
        bsm[i & 7][i >> 3] = b_dw[i];
    __syncthreads();
    int img = blockIdx.y;
    int t = blockIdx.x * 2 + (tid >> 7);          // token within image
    int cg = tid & 127;                           // uint4 channel-group
    int y = t >> 6, x = t & 63;
    const uint4* src = (const uint4*)h1 + (size_t)img * HWSZ * 128;
    float o[8];
#pragma unroll
    for (int c = 0; c < 8; c++) o[c] = bsm[c][cg];
#pragma unroll
    for (int dy = -1; dy <= 1; dy++) {
        int yy = y + dy;
        if (yy < 0 || yy >= HH) continue;         // wave-uniform
#pragma unroll
        for (int dx = -1; dx <= 1; dx++) {
            int xx = x + dx;
            if (xx < 0 || xx >= WW) continue;     // wave-uniform
            int k = (dy + 1) * 3 + (dx + 1);
            uint4 v = src[(size_t)(yy * WW + xx) * 128 + cg];
            const bf16* pv = (const bf16*)&v;
#pragma unroll
            for (int c = 0; c < 8; c++) o[c] += toF(pv[c]) * wsm[k][c][cg];
        }
    }
    uint4 pk;
    bf16* pb = (bf16*)&pk;
#pragma unroll
    for (int c = 0; c < 8; c++) pb[c] = toB(fmaxf(o[c], 0.f));
    ((uint4*)h1p + (size_t)img * HWSZ * 128)[(size_t)t * 128 + cg] = pk;
}

// ---------------------------------------------------------------------------
// out (NCHW fp32) = x1 + h2 (both token-major bf16)
__global__ void k_final(const bf16* __restrict__ x1, const bf16* __restrict__ h2,
                        float* __restrict__ out) {
    __shared__ float tile[32][33];
    int s0 = blockIdx.x * 32, c0 = blockIdx.y * 32, n = blockIdx.z;
    int tx = threadIdx.x, ty = threadIdx.y;
#pragma unroll
    for (int r = 0; r < 4; r++) {
        int s = s0 + ty + r * 8;
        size_t idx = ((size_t)n * HWSZ + s) * CDIM + c0 + tx;
        tile[tx][ty + r * 8] = toF(x1[idx]) + toF(h2[idx]);
    }
    __syncthreads();
#pragma unroll
    for (int r = 0; r < 4; r++) {
        int c = c0 + ty + r * 8;
        out[(size_t)n * CDIM * HWSZ + (size_t)c * HWSZ + s0 + tx] = tile[ty + r * 8][tx];
    }
}

// ---------------------------------------------------------------------------
extern "C" void kernel_launch(void* const* d_in, const int* in_sizes, int n_in,
                              void* d_out, int out_size, void* d_ws, size_t ws_size,
                              hipStream_t stream) {
    (void)in_sizes; (void)n_in; (void)out_size; (void)ws_size;
    const float* x      = (const float*)d_in[0];
    const float* wq     = (const float*)d_in[1];
    const float* gq     = (const float*)d_in[2];
    const float* bq     = (const float*)d_in[3];
    const float* wkv    = (const float*)d_in[4];
    const float* gkv    = (const float*)d_in[5];
    const float* bkv    = (const float*)d_in[6];
    const float* w_lepe = (const float*)d_in[7];
    const float* b_lepe = (const float*)d_in[8];
    const float* w_fc1  = (const float*)d_in[9];
    const float* g_fc1  = (const float*)d_in[10];
    const float* b_fc1  = (const float*)d_in[11];
    const float* w_dw   = (const float*)d_in[12];
    const float* b_dw   = (const float*)d_in[13];
    const float* w_fc2  = (const float*)d_in[14];
    const float* g_fc2  = (const float*)d_in[15];
    const float* b_fc2  = (const float*)d_in[16];

    char* ws = (char*)d_ws;
    bf16*  qkv    = (bf16*)(ws);
    bf16*  vpl    = (bf16*)(ws + 50331648);
    bf16*  attn   = (bf16*)(ws + 67108864);
    bf16*  xt     = (bf16*)(ws + 83886080);
    bf16*  x1     = (bf16*)(ws + 83886080);   // in-place over xt
    bf16*  h1     = (bf16*)(ws);              // phase B
    bf16*  h1p    = (bf16*)(ws + 33554432);
    bf16*  h2     = (bf16*)(ws + 67108864);
    float* xwin   = (float*)(ws + 100663296);
    float* qkwin  = (float*)(ws + 102760448);
    int*   tk     = (int*)(ws + 106954752);
    bf16*  wbqkv  = (bf16*)(ws + 106987520);
    bf16*  wbfc1  = (bf16*)(ws + 107380736);
    bf16*  wbfc2  = (bf16*)(ws + 107905024);
    float* bias768= (float*)(ws + 108429312);

    k_prep<<<2816, 256, 0, stream>>>(wq, gq, wkv, gkv, w_fc1, g_fc1, w_fc2, g_fc2,
                                     bq, bkv, wbqkv, wbfc1, wbfc2, bias768);
    k_xt<<<dim3(128, 8, 8), dim3(32, 8), 0, stream>>>(x, xt);
    k_xwin<<<2048, 256, 0, stream>>>(x, xwin);
    k_qkwin<<<dim3(32, 8), 256, 0, stream>>>(xwin, wq, wkv, gq, bq, gkv, bkv, qkwin);
    k_route<<<2048, 256, 0, stream>>>(qkwin, tk);
    k_mfma<128, 128, 1><<<dim3(256, 6), 256, 0, stream>>>(
        xt, wbqkv, bias768, qkv, vpl, TT, QKVD, CDIM);
    k_lepe_pl<<<2048, 256, 0, stream>>>(vpl, w_lepe, b_lepe);
    k_attn<<<2048, 256, 0, stream>>>(qkv, tk, attn);
    k_x1<<<dim3(128, 8, 8), dim3(32, 8), 0, stream>>>(xt, vpl, attn, x1);
    for (int c = 0; c < 2; c++) {
        bf16* x1c = x1 + (size_t)c * 16384 * CDIM;
        bf16* h2c = h2 + (size_t)c * 16384 * CDIM;
        k_mfma<128, 128, 0><<<dim3(128, 8), 256, 0, stream>>>(
            x1c, wbfc1, b_fc1, h1, nullptr, 16384, HID, CDIM);
        k_dw3_t<<<dim3(2048, 4), 256, 0, stream>>>(h1, w_dw, b_dw, h1p);
        k_mfma<64, 128, 0><<<dim3(256, 2), 256, 0, stream>>>(
            h1p, wbfc2, b_fc2, h2c, nullptr, 16384, CDIM, HID);
    }
    k_final<<<dim3(128, 8, 8), dim3(32, 8), 0, stream>>>(x1, h2, (float*)d_out);
}

// Round 8
// 463.916 us; speedup vs baseline: 1.3913x; 1.3913x over previous
//
#include <hip/hip_runtime.h>
#include <hip/hip_bf16.h>

#define NBATCH 8
#define CDIM 256
#define HH 64
#define WW 64
#define HWSZ 4096
#define TT 32768        // NBATCH * HWSZ tokens
#define QKVD 768        // q(256) | k(256) | v(256)
#define TOPK 4
#define HID 1024
#define ATTN_SCALE 0.0625f   // 256^-0.5

typedef __hip_bfloat16 bf16;
typedef __attribute__((ext_vector_type(8))) short s8v;   // 8 bf16 = 4 VGPR
typedef __attribute__((ext_vector_type(4))) float f4v;   // MFMA acc

__device__ __forceinline__ float toF(bf16 v) { return __bfloat162float(v); }
__device__ __forceinline__ bf16  toB(float v) { return __float2bfloat16(v); }

// ---------------------------------------------------------------------------
// Prep: fold gamma into weights, cast to bf16; concat qkv bias; and build
// wdwT: per-cg-contiguous dw3 weights+bias fp32: wdwT[cg*80 + c*9 + k],
// bias at wdwT[cg*80 + 72 + c]  (40 KB total).
__global__ void k_prep(const float* __restrict__ wq, const float* __restrict__ gq,
                       const float* __restrict__ wkv, const float* __restrict__ gkv,
                       const float* __restrict__ wfc1, const float* __restrict__ gfc1,
                       const float* __restrict__ wfc2, const float* __restrict__ gfc2,
                       const float* __restrict__ bq, const float* __restrict__ bkv,
                       const float* __restrict__ w_dw, const float* __restrict__ b_dw,
                       bf16* __restrict__ wbqkv, bf16* __restrict__ wbfc1,
                       bf16* __restrict__ wbfc2, float* __restrict__ bias768,
                       float* __restrict__ wdwT) {
    int i = blockIdx.x * 256 + threadIdx.x;
    if (i < 196608) {                       // wbqkv [768][256]
        int r = i >> 8;
        float g = (r < 256) ? gq[r] : gkv[r - 256];
        float w = (r < 256) ? wq[i] : wkv[i - 65536];
        wbqkv[i] = toB(w * g);
        if (i < 768) bias768[i] = (i < 256) ? bq[i] : bkv[i - 256];
    } else if (i < 458752) {                // wbfc1 [1024][256]
        int j = i - 196608;
        wbfc1[j] = toB(wfc1[j] * gfc1[j >> 8]);
    } else if (i < 720896) {                // wbfc2 [256][1024]
        int j = i - 458752;
        wbfc2[j] = toB(wfc2[j] * gfc2[j >> 10]);
    } else if (i < 731136) {                // wdwT [128][80]
        int j = i - 720896;
        int cg = j / 80, r = j - cg * 80;
        wdwT[j] = (r < 72) ? w_dw[(cg * 8 + r / 9) * 9 + (r % 9)]
                           : b_dw[cg * 8 + (r - 72)];
    }
}

// ---------------------------------------------------------------------------
// x NCHW fp32 -> token-major bf16 xt[m][c]
__global__ void k_xt(const float* __restrict__ x, bf16* __restrict__ xt) {
    __shared__ float tile[32][33];
    int s0 = blockIdx.x * 32, c0 = blockIdx.y * 32, n = blockIdx.z;
    int tx = threadIdx.x, ty = threadIdx.y;
#pragma unroll
    for (int r = 0; r < 4; r++)
        tile[ty + r * 8][tx] = x[(size_t)n * CDIM * HWSZ + (size_t)(c0 + ty + r * 8) * HWSZ + s0 + tx];
    __syncthreads();
#pragma unroll
    for (int r = 0; r < 4; r++)
        xt[((size_t)n * HWSZ + s0 + ty + r * 8) * CDIM + c0 + tx] = toB(tile[tx][ty + r * 8]);
}

// ---------------------------------------------------------------------------
// Window means of x (fp32-exact routing path). Block=(n,c), thread=window p.
__global__ void k_xwin(const float* __restrict__ x, float* __restrict__ xwin) {
    int b = blockIdx.x;
    int n = b >> 8, c = b & 255;
    int p = threadIdx.x, wy = p >> 4, wx = p & 15;
    const float* pl = x + ((size_t)n * CDIM + c) * HWSZ;
    float s = 0.f;
#pragma unroll
    for (int dy = 0; dy < 4; dy++)
#pragma unroll
        for (int dx = 0; dx < 4; dx++)
            s += pl[(wy * 4 + dy) * WW + wx * 4 + dx];
    xwin[((size_t)(n << 8) + p) * 256 + c] = s * 0.0625f;
}

// ---------------------------------------------------------------------------
// qkwin[m][0:512] = (xwin @ [wq|wk]^T)*g + b  (fp32 vector GEMM, M=2048 K=256)
__global__ void k_qkwin(const float* __restrict__ xwin,
                        const float* __restrict__ wq, const float* __restrict__ wkv,
                        const float* __restrict__ gq, const float* __restrict__ bq,
                        const float* __restrict__ gkv, const float* __restrict__ bkv,
                        float* __restrict__ qkwin) {
    __shared__ float As[16][68];
    __shared__ float Bs[16][68];
    int m0 = blockIdx.x * 64, n0 = blockIdx.y * 64;
    int tid = threadIdx.x;
    int tx = tid & 15, ty = tid >> 4;
    float acc[4][4] = {};
    for (int k0 = 0; k0 < 256; k0 += 16) {
#pragma unroll
        for (int r = 0; r < 4; r++) {
            int lin = tid + r * 256;
            int row = lin >> 4, kk = lin & 15;
            As[kk][row] = xwin[(size_t)(m0 + row) * 256 + k0 + kk];
            int n = n0 + row;
            const float* wr = (n < 256) ? (wq + (size_t)n * 256) : (wkv + (size_t)(n - 256) * 256);
            Bs[kk][row] = wr[k0 + kk];
        }
        __syncthreads();
#pragma unroll
        for (int kk = 0; kk < 16; kk++) {
            float a[4], bb[4];
#pragma unroll
            for (int i = 0; i < 4; i++) a[i] = As[kk][tx * 4 + i];
#pragma unroll
            for (int j = 0; j < 4; j++) bb[j] = Bs[kk][ty * 4 + j];
#pragma unroll
            for (int i = 0; i < 4; i++)
#pragma unroll
                for (int j = 0; j < 4; j++) acc[i][j] += a[i] * bb[j];
        }
        __syncthreads();
    }
#pragma unroll
    for (int j = 0; j < 4; j++) {
        int n = n0 + ty * 4 + j;
        float gg = (n < 256) ? gq[n] : gkv[n - 256];
        float bb = (n < 256) ? bq[n] : bkv[n - 256];
#pragma unroll
        for (int i = 0; i < 4; i++)
            qkwin[(size_t)(m0 + tx * 4 + i) * 512 + n] = acc[i][j] * gg + bb;
    }
}

// ---------------------------------------------------------------------------
// Routing: top-4 over 256 windows (ties -> lower index, as jax top_k).
__global__ void k_route(const float* __restrict__ qkwin, int* __restrict__ topk) {
    __shared__ float qrow[256];
    __shared__ float vals[256];
    __shared__ float rv[256];
    __shared__ int ri[256];
    int b = blockIdx.x;
    int n = b >> 8, pq = b & 255;
    int tid = threadIdx.x;
    qrow[tid] = qkwin[((size_t)(n << 8) + pq) * 512 + tid];
    __syncthreads();
    const float* krow = qkwin + ((size_t)(n << 8) + tid) * 512 + 256;
    float dot = 0.f;
    for (int o = 0; o < 256; o++) dot += qrow[o] * krow[o];
    vals[tid] = dot;
    __syncthreads();
    for (int sel = 0; sel < TOPK; sel++) {
        rv[tid] = vals[tid];
        ri[tid] = tid;
        __syncthreads();
        for (int off = 128; off > 0; off >>= 1) {
            if (tid < off) {
                if (rv[tid + off] > rv[tid] ||
                    (rv[tid + off] == rv[tid] && ri[tid + off] < ri[tid])) {
                    rv[tid] = rv[tid + off];
                    ri[tid] = ri[tid + off];
                }
            }
            __syncthreads();
        }
        if (tid == 0) {
            topk[((size_t)(n << 8) + pq) * TOPK + sel] = ri[0];
            vals[ri[0]] = -INFINITY;
        }
        __syncthreads();
    }
}

// ---------------------------------------------------------------------------
// MFMA GEMM: C[m][n] = A[m][k] * Wb[n][k] + bias[n].  A token-major bf16,
// Wb bf16 (gamma folded), bias fp32, out token-major bf16.
// OUTMODE 1 (qkv): cols >= 512 additionally stored planar to out2 (V for LEPE).
template <int BM, int BN, int OUTMODE>
__global__ __launch_bounds__(256) void k_mfma(const bf16* __restrict__ A,
                                              const bf16* __restrict__ Wb,
                                              const float* __restrict__ bias,
                                              bf16* __restrict__ out,
                                              bf16* __restrict__ out2,
                                              int M, int N, int K) {
    constexpr int WROWS = BM / 2, WCOLS = BN / 2;     // per-wave quadrant
    constexpr int WM = WROWS / 16, WN = WCOLS / 16;   // 16x16 tiles per wave
    constexpr int CA = (BM * 4) / 256;                // s8v chunks/thread for A
    constexpr int CB = (BN * 4) / 256;
    __shared__ bf16 As[BM * 32];
    __shared__ bf16 Bs[BN * 32];
    int m0 = blockIdx.x * BM, n0 = blockIdx.y * BN;
    int tid = threadIdx.x;
    int w = tid >> 6, lane = tid & 63;
    int wr = w >> 1, wc = w & 1;
    int lm = lane & 15, lq = lane >> 4;
    f4v acc[WM][WN];
#pragma unroll
    for (int i = 0; i < WM; i++)
#pragma unroll
        for (int j = 0; j < WN; j++) acc[i][j] = (f4v){0.f, 0.f, 0.f, 0.f};

    for (int k0 = 0; k0 < K; k0 += 32) {
        s8v va[CA], vb[CB];
#pragma unroll
        for (int q = 0; q < CA; q++) {
            int c = tid + q * 256, row = c >> 2, col = c & 3;
            va[q] = *(const s8v*)(A + (size_t)(m0 + row) * K + k0 + col * 8);
        }
#pragma unroll
        for (int q = 0; q < CB; q++) {
            int c = tid + q * 256, row = c >> 2, col = c & 3;
            vb[q] = *(const s8v*)(Wb + (size_t)(n0 + row) * K + k0 + col * 8);
        }
        __syncthreads();   // previous iter's LDS reads done
#pragma unroll
        for (int q = 0; q < CA; q++) {
            int c = tid + q * 256, row = c >> 2, col = c & 3;
            *(s8v*)&As[row * 32 + col * 8] = va[q];
        }
#pragma unroll
        for (int q = 0; q < CB; q++) {
            int c = tid + q * 256, row = c >> 2, col = c & 3;
            *(s8v*)&Bs[row * 32 + col * 8] = vb[q];
        }
        __syncthreads();
        s8v af[WM], bfr[WN];
#pragma unroll
        for (int i = 0; i < WM; i++)
            af[i] = *(const s8v*)&As[(wr * WROWS + i * 16 + lm) * 32 + lq * 8];
#pragma unroll
        for (int j = 0; j < WN; j++)
            bfr[j] = *(const s8v*)&Bs[(wc * WCOLS + j * 16 + lm) * 32 + lq * 8];
#pragma unroll
        for (int i = 0; i < WM; i++)
#pragma unroll
            for (int j = 0; j < WN; j++)
                acc[i][j] = __builtin_amdgcn_mfma_f32_16x16x32_bf16(af[i], bfr[j], acc[i][j], 0, 0, 0);
    }
    // Epilogue. C/D layout: col(n) = lane&15, row(m) = (lane>>4)*4 + reg.
#pragma unroll
    for (int j = 0; j < WN; j++) {
        int n = n0 + wc * WCOLS + j * 16 + lm;
        float bb = bias[n];
#pragma unroll
        for (int i = 0; i < WM; i++) {
            int mb = m0 + wr * WROWS + i * 16 + lq * 4;
#pragma unroll
            for (int r = 0; r < 4; r++)
                out[(size_t)(mb + r) * N + n] = toB(acc[i][j][r] + bb);
            if (OUTMODE == 1 && n >= 512) {   // planar V copy (lane-uniform branch)
                bf16* dst = out2 + ((size_t)(mb >> 12) * CDIM + (n - 512)) * HWSZ + (mb & 4095);
#pragma unroll
                for (int r = 0; r < 4; r++) dst[r] = toB(acc[i][j][r] + bb);
            }
        }
    }
}

// ---------------------------------------------------------------------------
// LEPE planar, IN-PLACE on vpl: block owns plane (n,c); 64x64 plane in LDS.
__global__ void k_lepe_pl(bf16* __restrict__ vpl, const float* __restrict__ w_lepe,
                          const float* __restrict__ b_lepe) {
    __shared__ float pl[HWSZ];
    int b = blockIdx.x;
    int n = b >> 8, c = b & 255;
    int tid = threadIdx.x;
    bf16* plane = vpl + ((size_t)n * CDIM + c) * HWSZ;
#pragma unroll
    for (int k = 0; k < 16; k++) pl[tid + k * 256] = toF(plane[tid + k * 256]);
    float wreg[25];
#pragma unroll
    for (int i = 0; i < 25; i++) wreg[i] = w_lepe[c * 25 + i];
    float bias = b_lepe[c];
    __syncthreads();
#pragma unroll
    for (int k = 0; k < 16; k++) {
        int s = tid + k * 256;
        int y = s >> 6, xx0 = s & 63;
        float acc = bias;
#pragma unroll
        for (int dy = -2; dy <= 2; dy++) {
            int yy = y + dy;
            if (yy < 0 || yy >= HH) continue;
#pragma unroll
            for (int dx = -2; dx <= 2; dx++) {
                int xx = xx0 + dx;
                if (xx < 0 || xx >= WW) continue;
                acc += pl[yy * 64 + xx] * wreg[(dy + 2) * 5 + (dx + 2)];
            }
        }
        plane[s] = toB(acc);
    }
}

// ---------------------------------------------------------------------------
// MFMA attention: one block per (n, window). 256 thr = 4 waves, 2 heads/wave.
// S^T = K*Q^T (4 mfma) -> full softmax (all 64 keys present) -> P via LDS ->
// O = P*V^T (4 mfma) with V staged TRANSPOSED in LDS.
__global__ __launch_bounds__(256) void k_attn(const bf16* __restrict__ qkv,
                                              const int* __restrict__ topk,
                                              bf16* __restrict__ attnout) {
    __shared__ bf16 vst[256][72];      // V^T [dim][key], pad 72 (rows 144 B, 16-aligned)
    __shared__ bf16 plds[4][16][72];   // per-wave P [tok][key]
    __shared__ float lsm[4][16];       // per-wave softmax denominator per tok
    __shared__ int toks[64];           // routed key -> token index (within image)
    int b = blockIdx.x;
    int n = b >> 8, p = b & 255;
    int wy = p >> 4, wx = p & 15;
    int tid = threadIdx.x;
    if (tid < 64) {
        int rp = topk[((size_t)(n << 8) + p) * TOPK + (tid >> 4)] & 255;
        int st = tid & 15;
        toks[tid] = ((rp >> 4) * 4 + (st >> 2)) * WW + (rp & 15) * 4 + (st & 3);
    }
    __syncthreads();
    const bf16* qbase = qkv + (size_t)n * HWSZ * QKVD;
    // stage V^T: per pass, 64 keys x 32 dims. kt fast -> conflict-free-ish writes.
    {
        int kt = tid & 63, jj = tid >> 6;
#pragma unroll
        for (int pass = 0; pass < 8; pass++) {
            int d0 = pass * 32 + jj * 8;
            uint4 v = *(const uint4*)(qbase + (size_t)toks[kt] * QKVD + 512 + d0);
            const bf16* pv = (const bf16*)&v;
#pragma unroll
            for (int e = 0; e < 8; e++) vst[d0 + e][kt] = pv[e];
        }
    }
    __syncthreads();
    int w = tid >> 6, lane = tid & 63;
    int ln = lane & 15, lq = lane >> 4;
    int myS = (wy * 4 + (ln >> 2)) * WW + wx * 4 + (ln & 3);   // own-window token ln
    const f4v fz = {0.f, 0.f, 0.f, 0.f};
    for (int hh = 0; hh < 2; hh++) {
        int h = w * 2 + hh;
        // B-frag: Q[tok=ln][k=lq*8+j] straight from global
        s8v qf = *(const s8v*)(qbase + (size_t)myS * QKVD + h * 32 + lq * 8);
        // A-frags: K[key][k] per 16-key tile; S^T tiles
        f4v st4[4];
#pragma unroll
        for (int t = 0; t < 4; t++) {
            s8v kf = *(const s8v*)(qbase + (size_t)toks[t * 16 + ln] * QKVD + 256 + h * 32 + lq * 8);
            st4[t] = __builtin_amdgcn_mfma_f32_16x16x32_bf16(kf, qf, fz, 0, 0, 0);
        }
        // lane holds S[key = t*16+lq*4+r][tok = ln]; softmax over keys
        float mx = -INFINITY;
#pragma unroll
        for (int t = 0; t < 4; t++)
#pragma unroll
            for (int r = 0; r < 4; r++) mx = fmaxf(mx, st4[t][r]);
        mx = fmaxf(mx, __shfl_xor(mx, 16));
        mx = fmaxf(mx, __shfl_xor(mx, 32));
        mx *= ATTN_SCALE;
        float sum = 0.f;
#pragma unroll
        for (int t = 0; t < 4; t++)
#pragma unroll
            for (int r = 0; r < 4; r++) {
                float pp = __expf(st4[t][r] * ATTN_SCALE - mx);
                sum += pp;
                plds[w][ln][t * 16 + lq * 4 + r] = toB(pp);
            }
        sum += __shfl_xor(sum, 16);
        sum += __shfl_xor(sum, 32);
        if (lq == 0) lsm[w][ln] = sum;
        __syncthreads();
        // PV: A = P[tok][key] frags, B = V^T[dim][key] frags
        s8v ap0 = *(const s8v*)&plds[w][ln][lq * 8];
        s8v ap1 = *(const s8v*)&plds[w][ln][32 + lq * 8];
#pragma unroll
        for (int dt = 0; dt < 2; dt++) {
            int dim = h * 32 + dt * 16 + ln;
            s8v vv0 = *(const s8v*)&vst[dim][lq * 8];
            s8v vv1 = *(const s8v*)&vst[dim][32 + lq * 8];
            f4v o = __builtin_amdgcn_mfma_f32_16x16x32_bf16(ap0, vv0, fz, 0, 0, 0);
            o = __builtin_amdgcn_mfma_f32_16x16x32_bf16(ap1, vv1, o, 0, 0, 0);
            // C: col = dim_local(ln), row = tok = lq*4+r
#pragma unroll
            for (int r = 0; r < 4; r++) {
                int t = lq * 4 + r;
                float linv = 1.f / lsm[w][t];
                int s = (wy * 4 + (t >> 2)) * WW + wx * 4 + (t & 3);
                attnout[((size_t)n * HWSZ + s) * CDIM + dim] = toB(o[r] * linv);
            }
        }
        __syncthreads();   // before next head reuses plds/lsm
    }
}

// ---------------------------------------------------------------------------
// x1[s][c] = xt[s][c] + attn[s][c] + lepe_planar[c][s]  (in-place over xt)
__global__ void k_x1(const bf16* __restrict__ xt, const bf16* __restrict__ lepe,
                     const bf16* __restrict__ attnout, bf16* __restrict__ x1) {
    __shared__ float tile[32][33];
    int s0 = blockIdx.x * 32, c0 = blockIdx.y * 32, n = blockIdx.z;
    int tx = threadIdx.x, ty = threadIdx.y;
#pragma unroll
    for (int r = 0; r < 4; r++) {
        int c = c0 + ty + r * 8;
        tile[ty + r * 8][tx] = toF(lepe[((size_t)n * CDIM + c) * HWSZ + s0 + tx]);
    }
    __syncthreads();
#pragma unroll
    for (int r = 0; r < 4; r++) {
        int s = s0 + ty + r * 8;
        size_t idx = ((size_t)n * HWSZ + s) * CDIM + c0 + tx;
        x1[idx] = toB(toF(xt[idx]) + toF(attnout[idx]) + tile[tx][ty + r * 8]);
    }
}

// ---------------------------------------------------------------------------
// Depthwise 3x3 + bias + ReLU, token-major in/out, channels lane-fast,
// NO LDS: per-thread weights in registers (from pre-transposed wdwT),
// amortized over 8 consecutive x-positions (wave-uniform x).
__global__ __launch_bounds__(256) void k_dw3_t(const bf16* __restrict__ h1,
                                               const float* __restrict__ wdwT,
                                               bf16* __restrict__ h1p) {
    int tid = threadIdx.x;
    int cg = tid & 127;                 // uint4 channel-group (lane-fast)
    int slot = tid >> 7;                // 0..1
    int seg = blockIdx.x;               // 0..255: row y = seg>>2, x-quarter = seg&3
    int img = blockIdx.y;               // 0..3 (chunk-local)
    int y = seg >> 2;
    int x0 = ((seg & 3) << 4) + (slot << 3);   // 8 tokens per thread
    const float* wp = wdwT + cg * 80;
    float w[72], bias[8];
#pragma unroll
    for (int i = 0; i < 72; i++) w[i] = wp[i];
#pragma unroll
    for (int c = 0; c < 8; c++) bias[c] = wp[72 + c];
    const uint4* src = (const uint4*)h1 + (size_t)img * HWSZ * 128;
    uint4* dst = (uint4*)h1p + (size_t)img * HWSZ * 128;
#pragma unroll
    for (int xi = 0; xi < 8; xi++) {
        int x = x0 + xi;                // wave-uniform
        float o[8];
#pragma unroll
        for (int c = 0; c < 8; c++) o[c] = bias[c];
#pragma unroll
        for (int dy = -1; dy <= 1; dy++) {
            int yy = y + dy;
            if (yy < 0 || yy >= HH) continue;       // wave-uniform
#pragma unroll
            for (int dx = -1; dx <= 1; dx++) {
                int xx = x + dx;
                if (xx < 0 || xx >= WW) continue;   // wave-uniform
                int k = (dy + 1) * 3 + (dx + 1);
                uint4 v = src[(size_t)(yy * WW + xx) * 128 + cg];
                const bf16* pv = (const bf16*)&v;
#pragma unroll
                for (int c = 0; c < 8; c++) o[c] += toF(pv[c]) * w[c * 9 + k];
            }
        }
        uint4 pk;
        bf16* pb = (bf16*)&pk;
#pragma unroll
        for (int c = 0; c < 8; c++) pb[c] = toB(fmaxf(o[c], 0.f));
        dst[(size_t)(y * WW + x) * 128 + cg] = pk;
    }
}

// ---------------------------------------------------------------------------
// out (NCHW fp32) = x1 + h2 (both token-major bf16)
__global__ void k_final(const bf16* __restrict__ x1, const bf16* __restrict__ h2,
                        float* __restrict__ out) {
    __shared__ float tile[32][33];
    int s0 = blockIdx.x * 32, c0 = blockIdx.y * 32, n = blockIdx.z;
    int tx = threadIdx.x, ty = threadIdx.y;
#pragma unroll
    for (int r = 0; r < 4; r++) {
        int s = s0 + ty + r * 8;
        size_t idx = ((size_t)n * HWSZ + s) * CDIM + c0 + tx;
        tile[tx][ty + r * 8] = toF(x1[idx]) + toF(h2[idx]);
    }
    __syncthreads();
#pragma unroll
    for (int r = 0; r < 4; r++) {
        int c = c0 + ty + r * 8;
        out[(size_t)n * CDIM * HWSZ + (size_t)c * HWSZ + s0 + tx] = tile[ty + r * 8][tx];
    }
}

// ---------------------------------------------------------------------------
extern "C" void kernel_launch(void* const* d_in, const int* in_sizes, int n_in,
                              void* d_out, int out_size, void* d_ws, size_t ws_size,
                              hipStream_t stream) {
    (void)in_sizes; (void)n_in; (void)out_size; (void)ws_size;
    const float* x      = (const float*)d_in[0];
    const float* wq     = (const float*)d_in[1];
    const float* gq     = (const float*)d_in[2];
    const float* bq     = (const float*)d_in[3];
    const float* wkv    = (const float*)d_in[4];
    const float* gkv    = (const float*)d_in[5];
    const float* bkv    = (const float*)d_in[6];
    const float* w_lepe = (const float*)d_in[7];
    const float* b_lepe = (const float*)d_in[8];
    const float* w_fc1  = (const float*)d_in[9];
    const float* g_fc1  = (const float*)d_in[10];
    const float* b_fc1  = (const float*)d_in[11];
    const float* w_dw   = (const float*)d_in[12];
    const float* b_dw   = (const float*)d_in[13];
    const float* w_fc2  = (const float*)d_in[14];
    const float* g_fc2  = (const float*)d_in[15];
    const float* b_fc2  = (const float*)d_in[16];

    char* ws = (char*)d_ws;
    bf16*  qkv    = (bf16*)(ws);
    bf16*  vpl    = (bf16*)(ws + 50331648);
    bf16*  attn   = (bf16*)(ws + 67108864);
    bf16*  xt     = (bf16*)(ws + 83886080);
    bf16*  x1     = (bf16*)(ws + 83886080);   // in-place over xt
    bf16*  h1     = (bf16*)(ws);              // phase B
    bf16*  h1p    = (bf16*)(ws + 33554432);
    bf16*  h2     = (bf16*)(ws + 67108864);
    float* xwin   = (float*)(ws + 100663296);
    float* qkwin  = (float*)(ws + 102760448);
    int*   tk     = (int*)(ws + 106954752);
    bf16*  wbqkv  = (bf16*)(ws + 106987520);
    bf16*  wbfc1  = (bf16*)(ws + 107380736);
    bf16*  wbfc2  = (bf16*)(ws + 107905024);
    float* bias768= (float*)(ws + 108429312);
    float* wdwT   = (float*)(ws + 108433408);  // 40 KB

    k_prep<<<2856, 256, 0, stream>>>(wq, gq, wkv, gkv, w_fc1, g_fc1, w_fc2, g_fc2,
                                     bq, bkv, w_dw, b_dw,
                                     wbqkv, wbfc1, wbfc2, bias768, wdwT);
    k_xt<<<dim3(128, 8, 8), dim3(32, 8), 0, stream>>>(x, xt);
    k_xwin<<<2048, 256, 0, stream>>>(x, xwin);
    k_qkwin<<<dim3(32, 8), 256, 0, stream>>>(xwin, wq, wkv, gq, bq, gkv, bkv, qkwin);
    k_route<<<2048, 256, 0, stream>>>(qkwin, tk);
    k_mfma<128, 128, 1><<<dim3(256, 6), 256, 0, stream>>>(
        xt, wbqkv, bias768, qkv, vpl, TT, QKVD, CDIM);
    k_lepe_pl<<<2048, 256, 0, stream>>>(vpl, w_lepe, b_lepe);
    k_attn<<<2048, 256, 0, stream>>>(qkv, tk, attn);
    k_x1<<<dim3(128, 8, 8), dim3(32, 8), 0, stream>>>(xt, vpl, attn, x1);
    for (int c = 0; c < 2; c++) {
        bf16* x1c = x1 + (size_t)c * 16384 * CDIM;
        bf16* h2c = h2 + (size_t)c * 16384 * CDIM;
        k_mfma<128, 128, 0><<<dim3(128, 8), 256, 0, stream>>>(
            x1c, wbfc1, b_fc1, h1, nullptr, 16384, HID, CDIM);
        k_dw3_t<<<dim3(256, 4), 256, 0, stream>>>(h1, wdwT, h1p);
        k_mfma<64, 128, 0><<<dim3(256, 2), 256, 0, stream>>>(
            h1p, wbfc2, b_fc2, h2c, nullptr, 16384, CDIM, HID);
    }
    k_final<<<dim3(128, 8, 8), dim3(32, 8), 0, stream>>>(x1, h2, (float*)d_out);
}

// Round 9
// 424.987 us; speedup vs baseline: 1.5187x; 1.0916x over previous
//
#include <hip/hip_runtime.h>
#include <hip/hip_bf16.h>

#define NBATCH 8
#define CDIM 256
#define HH 64
#define WW 64
#define HWSZ 4096
#define TT 32768        // NBATCH * HWSZ tokens
#define QKVD 768        // q(256) | k(256) | v(256)
#define TOPK 4
#define HID 1024
#define ATTN_SCALE 0.0625f   // 256^-0.5

typedef __hip_bfloat16 bf16;
typedef __attribute__((ext_vector_type(8))) short s8v;   // 8 bf16 = 4 VGPR
typedef __attribute__((ext_vector_type(4))) float f4v;   // MFMA acc

__device__ __forceinline__ float toF(bf16 v) { return __bfloat162float(v); }
__device__ __forceinline__ bf16  toB(float v) { return __float2bfloat16(v); }

// ---------------------------------------------------------------------------
// Prep: fold gamma into weights, cast to bf16; concat qkv bias; and build
// wdwT: per-cg-contiguous dw3 weights+bias fp32: wdwT[cg*80 + c*9 + k],
// bias at wdwT[cg*80 + 72 + c]  (40 KB total).
__global__ void k_prep(const float* __restrict__ wq, const float* __restrict__ gq,
                       const float* __restrict__ wkv, const float* __restrict__ gkv,
                       const float* __restrict__ wfc1, const float* __restrict__ gfc1,
                       const float* __restrict__ wfc2, const float* __restrict__ gfc2,
                       const float* __restrict__ bq, const float* __restrict__ bkv,
                       const float* __restrict__ w_dw, const float* __restrict__ b_dw,
                       bf16* __restrict__ wbqkv, bf16* __restrict__ wbfc1,
                       bf16* __restrict__ wbfc2, float* __restrict__ bias768,
                       float* __restrict__ wdwT) {
    int i = blockIdx.x * 256 + threadIdx.x;
    if (i < 196608) {                       // wbqkv [768][256]
        int r = i >> 8;
        float g = (r < 256) ? gq[r] : gkv[r - 256];
        float w = (r < 256) ? wq[i] : wkv[i - 65536];
        wbqkv[i] = toB(w * g);
        if (i < 768) bias768[i] = (i < 256) ? bq[i] : bkv[i - 256];
    } else if (i < 458752) {                // wbfc1 [1024][256]
        int j = i - 196608;
        wbfc1[j] = toB(wfc1[j] * gfc1[j >> 8]);
    } else if (i < 720896) {                // wbfc2 [256][1024]
        int j = i - 458752;
        wbfc2[j] = toB(wfc2[j] * gfc2[j >> 10]);
    } else if (i < 731136) {                // wdwT [128][80]
        int j = i - 720896;
        int cg = j / 80, r = j - cg * 80;
        wdwT[j] = (r < 72) ? w_dw[(cg * 8 + r / 9) * 9 + (r % 9)]
                           : b_dw[cg * 8 + (r - 72)];
    }
}

// ---------------------------------------------------------------------------
// x NCHW fp32 -> token-major bf16 xt[m][c]
__global__ void k_xt(const float* __restrict__ x, bf16* __restrict__ xt) {
    __shared__ float tile[32][33];
    int s0 = blockIdx.x * 32, c0 = blockIdx.y * 32, n = blockIdx.z;
    int tx = threadIdx.x, ty = threadIdx.y;
#pragma unroll
    for (int r = 0; r < 4; r++)
        tile[ty + r * 8][tx] = x[(size_t)n * CDIM * HWSZ + (size_t)(c0 + ty + r * 8) * HWSZ + s0 + tx];
    __syncthreads();
#pragma unroll
    for (int r = 0; r < 4; r++)
        xt[((size_t)n * HWSZ + s0 + ty + r * 8) * CDIM + c0 + tx] = toB(tile[tx][ty + r * 8]);
}

// ---------------------------------------------------------------------------
// Window means of x (fp32-exact routing path). Block=(n,c), thread=window p.
__global__ void k_xwin(const float* __restrict__ x, float* __restrict__ xwin) {
    int b = blockIdx.x;
    int n = b >> 8, c = b & 255;
    int p = threadIdx.x, wy = p >> 4, wx = p & 15;
    const float* pl = x + ((size_t)n * CDIM + c) * HWSZ;
    float s = 0.f;
#pragma unroll
    for (int dy = 0; dy < 4; dy++)
#pragma unroll
        for (int dx = 0; dx < 4; dx++)
            s += pl[(wy * 4 + dy) * WW + wx * 4 + dx];
    xwin[((size_t)(n << 8) + p) * 256 + c] = s * 0.0625f;
}

// ---------------------------------------------------------------------------
// qkwin[m][0:512] = (xwin @ [wq|wk]^T)*g + b  (fp32 vector GEMM, M=2048 K=256)
__global__ void k_qkwin(const float* __restrict__ xwin,
                        const float* __restrict__ wq, const float* __restrict__ wkv,
                        const float* __restrict__ gq, const float* __restrict__ bq,
                        const float* __restrict__ gkv, const float* __restrict__ bkv,
                        float* __restrict__ qkwin) {
    __shared__ float As[16][68];
    __shared__ float Bs[16][68];
    int m0 = blockIdx.x * 64, n0 = blockIdx.y * 64;
    int tid = threadIdx.x;
    int tx = tid & 15, ty = tid >> 4;
    float acc[4][4] = {};
    for (int k0 = 0; k0 < 256; k0 += 16) {
#pragma unroll
        for (int r = 0; r < 4; r++) {
            int lin = tid + r * 256;
            int row = lin >> 4, kk = lin & 15;
            As[kk][row] = xwin[(size_t)(m0 + row) * 256 + k0 + kk];
            int n = n0 + row;
            const float* wr = (n < 256) ? (wq + (size_t)n * 256) : (wkv + (size_t)(n - 256) * 256);
            Bs[kk][row] = wr[k0 + kk];
        }
        __syncthreads();
#pragma unroll
        for (int kk = 0; kk < 16; kk++) {
            float a[4], bb[4];
#pragma unroll
            for (int i = 0; i < 4; i++) a[i] = As[kk][tx * 4 + i];
#pragma unroll
            for (int j = 0; j < 4; j++) bb[j] = Bs[kk][ty * 4 + j];
#pragma unroll
            for (int i = 0; i < 4; i++)
#pragma unroll
                for (int j = 0; j < 4; j++) acc[i][j] += a[i] * bb[j];
        }
        __syncthreads();
    }
#pragma unroll
    for (int j = 0; j < 4; j++) {
        int n = n0 + ty * 4 + j;
        float gg = (n < 256) ? gq[n] : gkv[n - 256];
        float bb = (n < 256) ? bq[n] : bkv[n - 256];
#pragma unroll
        for (int i = 0; i < 4; i++)
            qkwin[(size_t)(m0 + tx * 4 + i) * 512 + n] = acc[i][j] * gg + bb;
    }
}

// ---------------------------------------------------------------------------
// Routing logits: per image, L[pq][key] = sum_c qwin[pq][c] * kwin[key][c].
// fp32 tiled GEMM, fully coalesced (q at qkwin[.][0:256], k at [.][256:512]).
__global__ void k_logits(const float* __restrict__ qkwin, float* __restrict__ logits) {
    __shared__ float As[16][68];
    __shared__ float Bs[16][68];
    int m0 = blockIdx.x * 64, n0 = blockIdx.y * 64, img = blockIdx.z;
    const float* base = qkwin + (size_t)(img << 8) * 512;
    int tid = threadIdx.x;
    int tx = tid & 15, ty = tid >> 4;
    float acc[4][4] = {};
    for (int k0 = 0; k0 < 256; k0 += 16) {
#pragma unroll
        for (int r = 0; r < 4; r++) {
            int lin = tid + r * 256;
            int row = lin >> 4, kk = lin & 15;
            As[kk][row] = base[(size_t)(m0 + row) * 512 + k0 + kk];
            Bs[kk][row] = base[(size_t)(n0 + row) * 512 + 256 + k0 + kk];
        }
        __syncthreads();
#pragma unroll
        for (int kk = 0; kk < 16; kk++) {
            float a[4], bb[4];
#pragma unroll
            for (int i = 0; i < 4; i++) a[i] = As[kk][tx * 4 + i];
#pragma unroll
            for (int j = 0; j < 4; j++) bb[j] = Bs[kk][ty * 4 + j];
#pragma unroll
            for (int i = 0; i < 4; i++)
#pragma unroll
                for (int j = 0; j < 4; j++) acc[i][j] += a[i] * bb[j];
        }
        __syncthreads();
    }
    float* Lr = logits + (size_t)(img << 8) * 256;
#pragma unroll
    for (int j = 0; j < 4; j++)
#pragma unroll
        for (int i = 0; i < 4; i++)
            Lr[(size_t)(m0 + tx * 4 + i) * 256 + n0 + ty * 4 + j] = acc[i][j];
}

// ---------------------------------------------------------------------------
// Top-4 per row of 256 logits: one wave per row, float4 load, shuffle argmax,
// jax tie-break (lower index wins). No __syncthreads.
__global__ __launch_bounds__(256) void k_topk(const float* __restrict__ logits,
                                              int* __restrict__ topk) {
    int row = blockIdx.x * 4 + (threadIdx.x >> 6);
    int lane = threadIdx.x & 63;
    float4 v4 = *(const float4*)(logits + (size_t)row * 256 + lane * 4);
    float v[4] = {v4.x, v4.y, v4.z, v4.w};
#pragma unroll
    for (int sel = 0; sel < TOPK; sel++) {
        float mv = v[0]; int mi = lane * 4;
#pragma unroll
        for (int j = 1; j < 4; j++)
            if (v[j] > mv) { mv = v[j]; mi = lane * 4 + j; }
#pragma unroll
        for (int off = 1; off < 64; off <<= 1) {
            float ov = __shfl_xor(mv, off);
            int oi = __shfl_xor(mi, off);
            if (ov > mv || (ov == mv && oi < mi)) { mv = ov; mi = oi; }
        }
        if (lane == 0) topk[(size_t)row * TOPK + sel] = mi;
        if ((mi >> 2) == lane) v[mi & 3] = -INFINITY;
    }
}

// ---------------------------------------------------------------------------
// MFMA GEMM: C[m][n] = A[m][k] * Wb[n][k] + bias[n].  A token-major bf16,
// Wb bf16 (gamma folded), bias fp32, out token-major bf16.
// OUTMODE 1 (qkv): cols >= 512 additionally stored planar to out2 (V for LEPE).
template <int BM, int BN, int OUTMODE>
__global__ __launch_bounds__(256) void k_mfma(const bf16* __restrict__ A,
                                              const bf16* __restrict__ Wb,
                                              const float* __restrict__ bias,
                                              bf16* __restrict__ out,
                                              bf16* __restrict__ out2,
                                              int M, int N, int K) {
    constexpr int WROWS = BM / 2, WCOLS = BN / 2;     // per-wave quadrant
    constexpr int WM = WROWS / 16, WN = WCOLS / 16;   // 16x16 tiles per wave
    constexpr int CA = (BM * 4) / 256;                // s8v chunks/thread for A
    constexpr int CB = (BN * 4) / 256;
    __shared__ bf16 As[BM * 32];
    __shared__ bf16 Bs[BN * 32];
    int m0 = blockIdx.x * BM, n0 = blockIdx.y * BN;
    int tid = threadIdx.x;
    int w = tid >> 6, lane = tid & 63;
    int wr = w >> 1, wc = w & 1;
    int lm = lane & 15, lq = lane >> 4;
    f4v acc[WM][WN];
#pragma unroll
    for (int i = 0; i < WM; i++)
#pragma unroll
        for (int j = 0; j < WN; j++) acc[i][j] = (f4v){0.f, 0.f, 0.f, 0.f};

    for (int k0 = 0; k0 < K; k0 += 32) {
        s8v va[CA], vb[CB];
#pragma unroll
        for (int q = 0; q < CA; q++) {
            int c = tid + q * 256, row = c >> 2, col = c & 3;
            va[q] = *(const s8v*)(A + (size_t)(m0 + row) * K + k0 + col * 8);
        }
#pragma unroll
        for (int q = 0; q < CB; q++) {
            int c = tid + q * 256, row = c >> 2, col = c & 3;
            vb[q] = *(const s8v*)(Wb + (size_t)(n0 + row) * K + k0 + col * 8);
        }
        __syncthreads();   // previous iter's LDS reads done
#pragma unroll
        for (int q = 0; q < CA; q++) {
            int c = tid + q * 256, row = c >> 2, col = c & 3;
            *(s8v*)&As[row * 32 + col * 8] = va[q];
        }
#pragma unroll
        for (int q = 0; q < CB; q++) {
            int c = tid + q * 256, row = c >> 2, col = c & 3;
            *(s8v*)&Bs[row * 32 + col * 8] = vb[q];
        }
        __syncthreads();
        s8v af[WM], bfr[WN];
#pragma unroll
        for (int i = 0; i < WM; i++)
            af[i] = *(const s8v*)&As[(wr * WROWS + i * 16 + lm) * 32 + lq * 8];
#pragma unroll
        for (int j = 0; j < WN; j++)
            bfr[j] = *(const s8v*)&Bs[(wc * WCOLS + j * 16 + lm) * 32 + lq * 8];
#pragma unroll
        for (int i = 0; i < WM; i++)
#pragma unroll
            for (int j = 0; j < WN; j++)
                acc[i][j] = __builtin_amdgcn_mfma_f32_16x16x32_bf16(af[i], bfr[j], acc[i][j], 0, 0, 0);
    }
    // Epilogue. C/D layout: col(n) = lane&15, row(m) = (lane>>4)*4 + reg.
#pragma unroll
    for (int j = 0; j < WN; j++) {
        int n = n0 + wc * WCOLS + j * 16 + lm;
        float bb = bias[n];
#pragma unroll
        for (int i = 0; i < WM; i++) {
            int mb = m0 + wr * WROWS + i * 16 + lq * 4;
#pragma unroll
            for (int r = 0; r < 4; r++)
                out[(size_t)(mb + r) * N + n] = toB(acc[i][j][r] + bb);
            if (OUTMODE == 1 && n >= 512) {   // planar V copy (lane-uniform branch)
                bf16* dst = out2 + ((size_t)(mb >> 12) * CDIM + (n - 512)) * HWSZ + (mb & 4095);
#pragma unroll
                for (int r = 0; r < 4; r++) dst[r] = toB(acc[i][j][r] + bb);
            }
        }
    }
}

// ---------------------------------------------------------------------------
// LEPE planar, IN-PLACE on vpl: block owns plane (n,c); 64x64 plane in LDS.
__global__ void k_lepe_pl(bf16* __restrict__ vpl, const float* __restrict__ w_lepe,
                          const float* __restrict__ b_lepe) {
    __shared__ float pl[HWSZ];
    int b = blockIdx.x;
    int n = b >> 8, c = b & 255;
    int tid = threadIdx.x;
    bf16* plane = vpl + ((size_t)n * CDIM + c) * HWSZ;
#pragma unroll
    for (int k = 0; k < 16; k++) pl[tid + k * 256] = toF(plane[tid + k * 256]);
    float wreg[25];
#pragma unroll
    for (int i = 0; i < 25; i++) wreg[i] = w_lepe[c * 25 + i];
    float bias = b_lepe[c];
    __syncthreads();
#pragma unroll
    for (int k = 0; k < 16; k++) {
        int s = tid + k * 256;
        int y = s >> 6, xx0 = s & 63;
        float acc = bias;
#pragma unroll
        for (int dy = -2; dy <= 2; dy++) {
            int yy = y + dy;
            if (yy < 0 || yy >= HH) continue;
#pragma unroll
            for (int dx = -2; dx <= 2; dx++) {
                int xx = xx0 + dx;
                if (xx < 0 || xx >= WW) continue;
                acc += pl[yy * 64 + xx] * wreg[(dy + 2) * 5 + (dx + 2)];
            }
        }
        plane[s] = toB(acc);
    }
}

// ---------------------------------------------------------------------------
// MFMA attention: one block per (n, window). 256 thr = 4 waves, 2 heads/wave.
// S^T = K*Q^T (4 mfma) -> full softmax (all 64 keys present) -> P via LDS ->
// O = P*V^T (4 mfma) with V staged TRANSPOSED in LDS.
__global__ __launch_bounds__(256) void k_attn(const bf16* __restrict__ qkv,
                                              const int* __restrict__ topk,
                                              bf16* __restrict__ attnout) {
    __shared__ bf16 vst[256][72];      // V^T [dim][key], pad 72 (rows 144 B, 16-aligned)
    __shared__ bf16 plds[4][16][72];   // per-wave P [tok][key]
    __shared__ float lsm[4][16];       // per-wave softmax denominator per tok
    __shared__ int toks[64];           // routed key -> token index (within image)
    int b = blockIdx.x;
    int n = b >> 8, p = b & 255;
    int wy = p >> 4, wx = p & 15;
    int tid = threadIdx.x;
    if (tid < 64) {
        int rp = topk[((size_t)(n << 8) + p) * TOPK + (tid >> 4)] & 255;
        int st = tid & 15;
        toks[tid] = ((rp >> 4) * 4 + (st >> 2)) * WW + (rp & 15) * 4 + (st & 3);
    }
    __syncthreads();
    const bf16* qbase = qkv + (size_t)n * HWSZ * QKVD;
    // stage V^T: per pass, 64 keys x 32 dims. kt fast -> conflict-free-ish writes.
    {
        int kt = tid & 63, jj = tid >> 6;
#pragma unroll
        for (int pass = 0; pass < 8; pass++) {
            int d0 = pass * 32 + jj * 8;
            uint4 v = *(const uint4*)(qbase + (size_t)toks[kt] * QKVD + 512 + d0);
            const bf16* pv = (const bf16*)&v;
#pragma unroll
            for (int e = 0; e < 8; e++) vst[d0 + e][kt] = pv[e];
        }
    }
    __syncthreads();
    int w = tid >> 6, lane = tid & 63;
    int ln = lane & 15, lq = lane >> 4;
    int myS = (wy * 4 + (ln >> 2)) * WW + wx * 4 + (ln & 3);   // own-window token ln
    const f4v fz = {0.f, 0.f, 0.f, 0.f};
    for (int hh = 0; hh < 2; hh++) {
        int h = w * 2 + hh;
        // B-frag: Q[tok=ln][k=lq*8+j] straight from global
        s8v qf = *(const s8v*)(qbase + (size_t)myS * QKVD + h * 32 + lq * 8);
        // A-frags: K[key][k] per 16-key tile; S^T tiles
        f4v st4[4];
#pragma unroll
        for (int t = 0; t < 4; t++) {
            s8v kf = *(const s8v*)(qbase + (size_t)toks[t * 16 + ln] * QKVD + 256 + h * 32 + lq * 8);
            st4[t] = __builtin_amdgcn_mfma_f32_16x16x32_bf16(kf, qf, fz, 0, 0, 0);
        }
        // lane holds S[key = t*16+lq*4+r][tok = ln]; softmax over keys
        float mx = -INFINITY;
#pragma unroll
        for (int t = 0; t < 4; t++)
#pragma unroll
            for (int r = 0; r < 4; r++) mx = fmaxf(mx, st4[t][r]);
        mx = fmaxf(mx, __shfl_xor(mx, 16));
        mx = fmaxf(mx, __shfl_xor(mx, 32));
        mx *= ATTN_SCALE;
        float sum = 0.f;
#pragma unroll
        for (int t = 0; t < 4; t++)
#pragma unroll
            for (int r = 0; r < 4; r++) {
                float pp = __expf(st4[t][r] * ATTN_SCALE - mx);
                sum += pp;
                plds[w][ln][t * 16 + lq * 4 + r] = toB(pp);
            }
        sum += __shfl_xor(sum, 16);
        sum += __shfl_xor(sum, 32);
        if (lq == 0) lsm[w][ln] = sum;
        __syncthreads();
        // PV: A = P[tok][key] frags, B = V^T[dim][key] frags
        s8v ap0 = *(const s8v*)&plds[w][ln][lq * 8];
        s8v ap1 = *(const s8v*)&plds[w][ln][32 + lq * 8];
#pragma unroll
        for (int dt = 0; dt < 2; dt++) {
            int dim = h * 32 + dt * 16 + ln;
            s8v vv0 = *(const s8v*)&vst[dim][lq * 8];
            s8v vv1 = *(const s8v*)&vst[dim][32 + lq * 8];
            f4v o = __builtin_amdgcn_mfma_f32_16x16x32_bf16(ap0, vv0, fz, 0, 0, 0);
            o = __builtin_amdgcn_mfma_f32_16x16x32_bf16(ap1, vv1, o, 0, 0, 0);
            // C: col = dim_local(ln), row = tok = lq*4+r
#pragma unroll
            for (int r = 0; r < 4; r++) {
                int t = lq * 4 + r;
                float linv = 1.f / lsm[w][t];
                int s = (wy * 4 + (t >> 2)) * WW + wx * 4 + (t & 3);
                attnout[((size_t)n * HWSZ + s) * CDIM + dim] = toB(o[r] * linv);
            }
        }
        __syncthreads();   // before next head reuses plds/lsm
    }
}

// ---------------------------------------------------------------------------
// x1[s][c] = xt[s][c] + attn[s][c] + lepe_planar[c][s]  (in-place over xt)
__global__ void k_x1(const bf16* __restrict__ xt, const bf16* __restrict__ lepe,
                     const bf16* __restrict__ attnout, bf16* __restrict__ x1) {
    __shared__ float tile[32][33];
    int s0 = blockIdx.x * 32, c0 = blockIdx.y * 32, n = blockIdx.z;
    int tx = threadIdx.x, ty = threadIdx.y;
#pragma unroll
    for (int r = 0; r < 4; r++) {
        int c = c0 + ty + r * 8;
        tile[ty + r * 8][tx] = toF(lepe[((size_t)n * CDIM + c) * HWSZ + s0 + tx]);
    }
    __syncthreads();
#pragma unroll
    for (int r = 0; r < 4; r++) {
        int s = s0 + ty + r * 8;
        size_t idx = ((size_t)n * HWSZ + s) * CDIM + c0 + tx;
        x1[idx] = toB(toF(xt[idx]) + toF(attnout[idx]) + tile[tx][ty + r * 8]);
    }
}

// ---------------------------------------------------------------------------
// Depthwise 3x3 + bias + ReLU, token-major in/out, channels lane-fast,
// NO LDS: per-thread weights in registers (from pre-transposed wdwT),
// amortized over 8 consecutive x-positions (wave-uniform x).
__global__ __launch_bounds__(256) void k_dw3_t(const bf16* __restrict__ h1,
                                               const float* __restrict__ wdwT,
                                               bf16* __restrict__ h1p) {
    int tid = threadIdx.x;
    int cg = tid & 127;                 // uint4 channel-group (lane-fast)
    int slot = tid >> 7;                // 0..1
    int seg = blockIdx.x;               // 0..255: row y = seg>>2, x-quarter = seg&3
    int img = blockIdx.y;               // 0..3 (chunk-local)
    int y = seg >> 2;
    int x0 = ((seg & 3) << 4) + (slot << 3);   // 8 tokens per thread
    const float* wp = wdwT + cg * 80;
    float w[72], bias[8];
#pragma unroll
    for (int i = 0; i < 72; i++) w[i] = wp[i];
#pragma unroll
    for (int c = 0; c < 8; c++) bias[c] = wp[72 + c];
    const uint4* src = (const uint4*)h1 + (size_t)img * HWSZ * 128;
    uint4* dst = (uint4*)h1p + (size_t)img * HWSZ * 128;
#pragma unroll
    for (int xi = 0; xi < 8; xi++) {
        int x = x0 + xi;                // wave-uniform
        float o[8];
#pragma unroll
        for (int c = 0; c < 8; c++) o[c] = bias[c];
#pragma unroll
        for (int dy = -1; dy <= 1; dy++) {
            int yy = y + dy;
            if (yy < 0 || yy >= HH) continue;       // wave-uniform
#pragma unroll
            for (int dx = -1; dx <= 1; dx++) {
                int xx = x + dx;
                if (xx < 0 || xx >= WW) continue;   // wave-uniform
                int k = (dy + 1) * 3 + (dx + 1);
                uint4 v = src[(size_t)(yy * WW + xx) * 128 + cg];
                const bf16* pv = (const bf16*)&v;
#pragma unroll
                for (int c = 0; c < 8; c++) o[c] += toF(pv[c]) * w[c * 9 + k];
            }
        }
        uint4 pk;
        bf16* pb = (bf16*)&pk;
#pragma unroll
        for (int c = 0; c < 8; c++) pb[c] = toB(fmaxf(o[c], 0.f));
        dst[(size_t)(y * WW + x) * 128 + cg] = pk;
    }
}

// ---------------------------------------------------------------------------
// out (NCHW fp32) = x1 + h2 (both token-major bf16)
__global__ void k_final(const bf16* __restrict__ x1, const bf16* __restrict__ h2,
                        float* __restrict__ out) {
    __shared__ float tile[32][33];
    int s0 = blockIdx.x * 32, c0 = blockIdx.y * 32, n = blockIdx.z;
    int tx = threadIdx.x, ty = threadIdx.y;
#pragma unroll
    for (int r = 0; r < 4; r++) {
        int s = s0 + ty + r * 8;
        size_t idx = ((size_t)n * HWSZ + s) * CDIM + c0 + tx;
        tile[tx][ty + r * 8] = toF(x1[idx]) + toF(h2[idx]);
    }
    __syncthreads();
#pragma unroll
    for (int r = 0; r < 4; r++) {
        int c = c0 + ty + r * 8;
        out[(size_t)n * CDIM * HWSZ + (size_t)c * HWSZ + s0 + tx] = tile[ty + r * 8][tx];
    }
}

// ---------------------------------------------------------------------------
extern "C" void kernel_launch(void* const* d_in, const int* in_sizes, int n_in,
                              void* d_out, int out_size, void* d_ws, size_t ws_size,
                              hipStream_t stream) {
    (void)in_sizes; (void)n_in; (void)out_size; (void)ws_size;
    const float* x      = (const float*)d_in[0];
    const float* wq     = (const float*)d_in[1];
    const float* gq     = (const float*)d_in[2];
    const float* bq     = (const float*)d_in[3];
    const float* wkv    = (const float*)d_in[4];
    const float* gkv    = (const float*)d_in[5];
    const float* bkv    = (const float*)d_in[6];
    const float* w_lepe = (const float*)d_in[7];
    const float* b_lepe = (const float*)d_in[8];
    const float* w_fc1  = (const float*)d_in[9];
    const float* g_fc1  = (const float*)d_in[10];
    const float* b_fc1  = (const float*)d_in[11];
    const float* w_dw   = (const float*)d_in[12];
    const float* b_dw   = (const float*)d_in[13];
    const float* w_fc2  = (const float*)d_in[14];
    const float* g_fc2  = (const float*)d_in[15];
    const float* b_fc2  = (const float*)d_in[16];

    char* ws = (char*)d_ws;
    bf16*  qkv    = (bf16*)(ws);
    bf16*  vpl    = (bf16*)(ws + 50331648);
    bf16*  attn   = (bf16*)(ws + 67108864);
    bf16*  xt     = (bf16*)(ws + 83886080);
    bf16*  x1     = (bf16*)(ws + 83886080);   // in-place over xt
    bf16*  h1     = (bf16*)(ws);              // phase B
    bf16*  h1p    = (bf16*)(ws + 33554432);
    bf16*  h2     = (bf16*)(ws + 67108864);
    float* xwin   = (float*)(ws + 100663296);
    float* qkwin  = (float*)(ws + 102760448);
    int*   tk     = (int*)(ws + 106954752);
    bf16*  wbqkv  = (bf16*)(ws + 106987520);
    bf16*  wbfc1  = (bf16*)(ws + 107380736);
    bf16*  wbfc2  = (bf16*)(ws + 107905024);
    float* bias768= (float*)(ws + 108429312);
    float* wdwT   = (float*)(ws + 108433408);  // 40 KB
    float* logits = (float*)(ws + 108478464);  // 2 MB  (8*256*256 fp32)

    k_prep<<<2856, 256, 0, stream>>>(wq, gq, wkv, gkv, w_fc1, g_fc1, w_fc2, g_fc2,
                                     bq, bkv, w_dw, b_dw,
                                     wbqkv, wbfc1, wbfc2, bias768, wdwT);
    k_xt<<<dim3(128, 8, 8), dim3(32, 8), 0, stream>>>(x, xt);
    k_xwin<<<2048, 256, 0, stream>>>(x, xwin);
    k_qkwin<<<dim3(32, 8), 256, 0, stream>>>(xwin, wq, wkv, gq, bq, gkv, bkv, qkwin);
    k_logits<<<dim3(4, 4, 8), 256, 0, stream>>>(qkwin, logits);
    k_topk<<<512, 256, 0, stream>>>(logits, tk);
    k_mfma<128, 128, 1><<<dim3(256, 6), 256, 0, stream>>>(
        xt, wbqkv, bias768, qkv, vpl, TT, QKVD, CDIM);
    k_lepe_pl<<<2048, 256, 0, stream>>>(vpl, w_lepe, b_lepe);
    k_attn<<<2048, 256, 0, stream>>>(qkv, tk, attn);
    k_x1<<<dim3(128, 8, 8), dim3(32, 8), 0, stream>>>(xt, vpl, attn, x1);
    for (int c = 0; c < 2; c++) {
        bf16* x1c = x1 + (size_t)c * 16384 * CDIM;
        bf16* h2c = h2 + (size_t)c * 16384 * CDIM;
        k_mfma<128, 128, 0><<<dim3(128, 8), 256, 0, stream>>>(
            x1c, wbfc1, b_fc1, h1, nullptr, 16384, HID, CDIM);
        k_dw3_t<<<dim3(256, 4), 256, 0, stream>>>(h1, wdwT, h1p);
        k_mfma<64, 128, 0><<<dim3(256, 2), 256, 0, stream>>>(
            h1p, wbfc2, b_fc2, h2c, nullptr, 16384, CDIM, HID);
    }
    k_final<<<dim3(128, 8, 8), dim3(32, 8), 0, stream>>>(x1, h2, (float*)d_out);
}